// Round 10
// baseline (730.195 us; speedup 1.0000x reference)
//
#include <hip/hip_runtime.h>
#include <hip/hip_bf16.h>
#include <math.h>

#define B_SZ   1024
#define NROW   2048      // 2B
#define D_K    16384     // 128*128
#define SPLIT  8
#define KSEG   (D_K / SPLIT)   // 2048
#define NTILE  16
#define NPAIR  136
// fp8 rows scaled by 16 each => sim holds 256 * true_sim.
#define TEMP_SIM (2.0f / 256.0f)

typedef float f32x4  __attribute__((ext_vector_type(4)));
typedef float f32x16 __attribute__((ext_vector_type(16)));
typedef int   i32x4  __attribute__((ext_vector_type(4)));
typedef int   i32x8  __attribute__((ext_vector_type(8)));

typedef __attribute__((address_space(1))) unsigned int GU32;
typedef __attribute__((address_space(3))) unsigned int LU32;

__device__ __forceinline__ void async16(const void* g, void* l) {
  __builtin_amdgcn_global_load_lds((GU32*)(g), (LU32*)(l), 16, 0, 0);
}

// ---------------------------------------------------------------------------
// Kernel 1: per-row normalize -> fp8 e4m3 (x16) rn[2048][16384];
// zero sim / rsum / counters.
// ---------------------------------------------------------------------------
__global__ __launch_bounds__(512) void norm_kernel(
    const float* __restrict__ emb_i, const float* __restrict__ emb_j,
    unsigned char* __restrict__ rn, float* __restrict__ sim,
    float* __restrict__ rsum, unsigned int* __restrict__ cnt,
    unsigned int* __restrict__ tileCnt)
{
  const int b = blockIdx.x;
  const int t = threadIdx.x;
  const int c = t & 31;        // column group (4 cols)
  const int g = t >> 5;        // row group (8 rows), 0..15

  ((f32x4*)sim)[(size_t)b * 512 + t] = (f32x4){0.f, 0.f, 0.f, 0.f};
  if (b == 0) {
    for (int k = t; k < NROW; k += 512) rsum[k] = 0.f;
    for (int k = t; k < NPAIR; k += 512) tileCnt[k] = 0u;
    if (t == 0) *cnt = 0u;
  }

  const float* src = (b < B_SZ) ? (emb_i + (size_t)b * D_K)
                                : (emb_j + (size_t)(b - B_SZ) * D_K);

  f32x4 vals[8];
  f32x4 ss = (f32x4){0.f, 0.f, 0.f, 0.f};
#pragma unroll
  for (int mm = 0; mm < 8; ++mm) {
    f32x4 v = *(const f32x4*)(src + (size_t)(g * 8 + mm) * 128 + c * 4);
    vals[mm] = v;
    ss += v * v;
  }

  __shared__ f32x4 part[16][32];
  part[g][c] = ss;
  __syncthreads();
  f32x4 css = part[0][c];
#pragma unroll
  for (int gg = 1; gg < 16; ++gg) css += part[gg][c];

  f32x4 mcn, colz2;
#pragma unroll
  for (int k = 0; k < 4; ++k) {
    mcn[k] = fmaxf(sqrtf(css[k]), 1e-12f);
    colz2[k] = css[k] / (mcn[k] * mcn[k]);
  }
  float s = colz2[0] + colz2[1] + colz2[2] + colz2[3];
#pragma unroll
  for (int off = 1; off < 64; off <<= 1) s += __shfl_xor(s, off);
  const float rowfac = fmaxf(sqrtf(0.5f * s), 1e-8f);

  f32x4 scale;
#pragma unroll
  for (int k = 0; k < 4; ++k) scale[k] = 16.0f / (mcn[k] * rowfac);

  unsigned char* dst = rn + (size_t)b * D_K;
#pragma unroll
  for (int mm = 0; mm < 8; ++mm) {
    f32x4 sv = vals[mm] * scale;
    int p = 0;
    p = __builtin_amdgcn_cvt_pk_fp8_f32(sv[0], sv[1], p, false);
    p = __builtin_amdgcn_cvt_pk_fp8_f32(sv[2], sv[3], p, true);
    *(int*)(dst + (size_t)(g * 8 + mm) * 128 + c * 4) = p;
  }
}

// ---------------------------------------------------------------------------
// Kernel 2: sim(upper) += rn @ rn^T via MX-scaled fp8 (scale=1.0) 32x32x64
// MFMA (2x rate), 128x128 tile, BK=128, row-XOR LDS chunk swizzle.
// Fused: per-tile completion counter -> winner block computes that tile's
// exp-sums (device-coherent atomic reads); global counter -> last winner
// finalizes the loss. Grid (SPLIT, 136): XCD = linear%8 owns one K-segment.
// ---------------------------------------------------------------------------
__global__ __launch_bounds__(256) void gemm_sim_kernel(
    const unsigned char* __restrict__ rn, float* __restrict__ sim,
    float* __restrict__ rsum, unsigned int* __restrict__ cnt,
    unsigned int* __restrict__ tileCnt, float* __restrict__ out)
{
  const int tileIdx = blockIdx.y;
  int idx = tileIdx, tI = 0, rem = NTILE;
  while (idx >= rem) { idx -= rem; --rem; ++tI; }
  const int tJ = tI + idx;
  const bool diag = (tI == tJ);

  const int kBase = blockIdx.x * KSEG;
  const int t    = threadIdx.x;
  const int lane = t & 63;
  const int wave = t >> 6;
  const int wm = wave >> 1, wn = wave & 1;
  const int l31 = lane & 31, l5 = lane >> 5;

  __shared__ __align__(16) unsigned char As[128 * 128];  // 16 KB
  __shared__ __align__(16) unsigned char Bs[128 * 128];  // 16 KB

  // staging: instr i stages rows 32i..32i+31. thread t -> row 32i+(t>>3),
  // global 16B chunk gc=(t&7)^(row&7) stored at LDS chunk t&7.
  const int srow = t >> 3;
  const int gc   = (t & 7) ^ (srow & 7);
  const unsigned char* aGb = rn + (size_t)(tI * 128 + srow) * D_K + kBase + gc * 16;
  const unsigned char* bGb = rn + (size_t)(tJ * 128 + srow) * D_K + kBase + gc * 16;

  f32x16 acc[2][2];
#pragma unroll
  for (int mi = 0; mi < 2; ++mi)
#pragma unroll
    for (int ni = 0; ni < 2; ++ni)
      acc[mi][ni] = (f32x16)(0.f);

  for (int k0 = 0; k0 < KSEG; k0 += 128) {
    __syncthreads();
#pragma unroll
    for (int i = 0; i < 4; ++i) {
      async16(aGb + (size_t)(32 * i) * D_K + k0, &As[i * 4096 + t * 16]);
      async16(bGb + (size_t)(32 * i) * D_K + k0, &Bs[i * 4096 + t * 16]);
    }
    __syncthreads();

#pragma unroll
    for (int s = 0; s < 2; ++s) {
      // lane wants k-bytes [s*64 + l5*32, +32) of its row = global chunks
      // g, g+1 (g = s*4 + l5*2), stored at LDS chunks (g^r7), (g+1)^r7.
      const int g = s * 4 + l5 * 2;
      i32x8 af[2], bf[2];
#pragma unroll
      for (int mi = 0; mi < 2; ++mi) {
        const int row = wm * 64 + mi * 32 + l31;
        const int r7 = row & 7;
        i32x4 lo = *(const i32x4*)(&As[row * 128 + (g ^ r7) * 16]);
        i32x4 hi = *(const i32x4*)(&As[row * 128 + ((g + 1) ^ r7) * 16]);
        af[mi][0] = lo[0]; af[mi][1] = lo[1]; af[mi][2] = lo[2]; af[mi][3] = lo[3];
        af[mi][4] = hi[0]; af[mi][5] = hi[1]; af[mi][6] = hi[2]; af[mi][7] = hi[3];
      }
#pragma unroll
      for (int ni = 0; ni < 2; ++ni) {
        const int row = wn * 64 + ni * 32 + l31;
        const int r7 = row & 7;
        i32x4 lo = *(const i32x4*)(&Bs[row * 128 + (g ^ r7) * 16]);
        i32x4 hi = *(const i32x4*)(&Bs[row * 128 + ((g + 1) ^ r7) * 16]);
        bf[ni][0] = lo[0]; bf[ni][1] = lo[1]; bf[ni][2] = lo[2]; bf[ni][3] = lo[3];
        bf[ni][4] = hi[0]; bf[ni][5] = hi[1]; bf[ni][6] = hi[2]; bf[ni][7] = hi[3];
      }
#pragma unroll
      for (int mi = 0; mi < 2; ++mi)
#pragma unroll
        for (int ni = 0; ni < 2; ++ni)
          acc[mi][ni] = __builtin_amdgcn_mfma_scale_f32_32x32x64_f8f6f4(
              af[mi], bf[ni], acc[mi][ni], 0, 0,   // cbsz=0 (fp8), blgp=0 (fp8)
              0, 0x7F7F7F7F,                       // scale A = 1.0 (e8m0 127)
              0, 0x7F7F7F7F);                      // scale B = 1.0
    }
  }

  // epilogue: 32x32 C/D layout col=lane&31, row=(reg&3)+8*(reg>>2)+4*(lane>>5)
  const int iB = tI * 128 + wm * 64;
  const int jB = tJ * 128 + wn * 64;
#pragma unroll
  for (int mi = 0; mi < 2; ++mi) {
#pragma unroll
    for (int ni = 0; ni < 2; ++ni) {
#pragma unroll
      for (int reg = 0; reg < 16; ++reg) {
        const int i = iB + mi * 32 + (reg & 3) + 8 * (reg >> 2) + 4 * l5;
        const int j = jB + ni * 32 + l31;
        if (!diag || j >= i)
          atomicAdd(&sim[(size_t)i * NROW + j], acc[mi][ni][reg]);
      }
    }
  }

  // ---- per-tile completion: winner computes this tile's exp-sums ----
  __threadfence();
  __syncthreads();
  int* flag = (int*)Bs;   // LDS reuse (K-loop done)
  if (t == 0) flag[8] = (atomicAdd(&tileCnt[tileIdx], 1u) == SPLIT - 1);
  __syncthreads();
  if (!flag[8]) return;

  // loss-tile: coalesced-ish atomic reads; rsum[i] via wave reduce,
  // rsum[j] via LDS column reduce (symmetric read-side reuse).
  {
    const int w   = t >> 6;
    const int l   = t & 63;
    const int hf  = l >> 5;
    const int sub = l & 31;
    const int jb  = tJ * 128 + sub * 4;
    float* colacc = (float*)As;           // [8][128] = 4 KB scratch

    float ca[4] = {0.f, 0.f, 0.f, 0.f};
#pragma unroll
    for (int step = 0; step < 16; ++step) {
      const int r  = w * 32 + step * 2 + hf;
      const int gi = tI * 128 + r;
      float* base = &sim[(size_t)gi * NROW + jb];
      float e[4];
#pragma unroll
      for (int k = 0; k < 4; ++k) {
        const float v = atomicAdd(&base[k], 0.f);   // device-coherent read
        float ev = __expf(TEMP_SIM * v);
        if (diag && (jb + k <= gi)) ev = 0.f;       // mask lower + diagonal
        e[k] = ev;
        ca[k] += ev;
      }
      float rp = e[0] + e[1] + e[2] + e[3];
#pragma unroll
      for (int off = 1; off < 32; off <<= 1) rp += __shfl_xor(rp, off);
      if (sub == 0) atomicAdd(&rsum[gi], rp);
    }
#pragma unroll
    for (int k = 0; k < 4; ++k) colacc[(w * 2 + hf) * 128 + sub * 4 + k] = ca[k];
    __syncthreads();
    if (t < 128) {
      float s = 0.f;
#pragma unroll
      for (int q = 0; q < 8; ++q) s += colacc[q * 128 + t];
      atomicAdd(&rsum[tJ * 128 + t], s);   // mirror contribution (row j)
    }
  }

  // ---- global completion: last tile-winner finalizes ----
  __threadfence();
  __syncthreads();
  if (t == 0) flag[8] = (atomicAdd(cnt, 1u) == NPAIR - 1);
  __syncthreads();
  if (!flag[8]) return;

  float s = 0.f;
  for (int i = t; i < NROW; i += 256) {
    const int jp = (i < B_SZ) ? i + B_SZ : i - B_SZ;
    float* pp = (jp >= i) ? &sim[(size_t)i * NROW + jp] : &sim[(size_t)jp * NROW + i];
    const float pos = atomicAdd(pp, 0.f);
    const float rs  = atomicAdd(&rsum[i], 0.f);
    s += logf(rs) - TEMP_SIM * pos;
  }
#pragma unroll
  for (int off = 1; off < 64; off <<= 1) s += __shfl_xor(s, off);
  float* r = (float*)As;
  if ((t & 63) == 0) r[t >> 6] = s;
  __syncthreads();
  if (t == 0) out[0] = (r[0] + r[1] + r[2] + r[3]) * (1.0f / NROW);
}

extern "C" void kernel_launch(void* const* d_in, const int* in_sizes, int n_in,
                              void* d_out, int out_size, void* d_ws, size_t ws_size,
                              hipStream_t stream) {
  const float* emb_i = (const float*)d_in[0];
  const float* emb_j = (const float*)d_in[1];
  float* out = (float*)d_out;

  char* ws = (char*)d_ws;
  unsigned char* rn = (unsigned char*)ws;                 // 32 MB (fp8)
  float* sim  = (float*)(ws + (size_t)NROW * D_K);        // 16 MB
  float* rsum = sim + (size_t)NROW * NROW;                // 8 KB
  unsigned int* cnt = (unsigned int*)(rsum + NROW);
  unsigned int* tileCnt = cnt + 1;                        // 136 u32

  norm_kernel<<<dim3(NROW), dim3(512), 0, stream>>>(emb_i, emb_j, rn, sim,
                                                    rsum, cnt, tileCnt);
  gemm_sim_kernel<<<dim3(SPLIT, NPAIR), dim3(256), 0, stream>>>(
      rn, sim, rsum, cnt, tileCnt, out);
}